// Round 1
// baseline (958.893 us; speedup 1.0000x reference)
//
#include <hip/hip_runtime.h>
#include <math.h>

#define CIN 256
#define COUT 128
#define H0 64
#define W0 64
#define HU 128
#define WU 128
#define NB 2

// ---------------- Kernel 1: offset network (two 1x1-effective matmuls) + bilinear params ----------------
// lateral [N,128,1,1] -> h = relu(W1_center @ lat + b1) [N,64] -> off = tanh(W2_center @ h + b2) [N,18]
// Per (n, tap): iy = ky-1+floor(off_y), fy = frac(off_y); same for x.
__global__ void k_offset(const float* __restrict__ lat,
                         const float* __restrict__ w1, const float* __restrict__ b1,
                         const float* __restrict__ w2, const float* __restrict__ b2,
                         int* __restrict__ ipar, float* __restrict__ fpar) {
    __shared__ float h[NB][64];
    __shared__ float offv[NB][18];
    int t = threadIdx.x;
    if (t < NB * 64) {
        int n = t >> 6, o = t & 63;
        float s = b1[o];
        const float* ln = lat + n * COUT;
        for (int c = 0; c < COUT; ++c) s += ln[c] * w1[(o * COUT + c) * 9 + 4];  // center tap (1,1)
        h[n][o] = fmaxf(s, 0.f);
    }
    __syncthreads();
    if (t < NB * 18) {
        int n = t / 18, j = t % 18;
        float s = b2[j];
        for (int o = 0; o < 64; ++o) s += h[n][o] * w2[(j * 64 + o) * 9 + 4];
        float ov = tanhf(s);
        // guard against exact +-1.0 (floor would push corner out of the 5x5 halo)
        ov = fminf(fmaxf(ov, -0.999999f), 0.999999f);
        offv[n][j] = ov;
    }
    __syncthreads();
    if (t < NB * 18) {
        int n = t / 18, j = t % 18;
        int tap = j >> 1, d = j & 1;          // channel order: [tap][2], d=0 -> y, d=1 -> x
        float ov = offv[n][j];
        float fl = floorf(ov);
        int kc = d ? (tap % 3) : (tap / 3);   // kx : ky
        ipar[(n * 9 + tap) * 2 + d] = kc - 1 + (int)fl;
        fpar[(n * 9 + tap) * 2 + d] = ov - fl;
    }
}

// ---------------- Kernel 2: transpose trans_w [o][c][tap] -> wT [c][tap][o] ----------------
__global__ void k_wtrans(const float* __restrict__ w, float* __restrict__ wT) {
    int i = blockIdx.x * 256 + threadIdx.x;
    if (i >= CIN * COUT * 9) return;
    int o = i / (COUT * 9);
    int rem = i - o * (COUT * 9);
    int c = rem / 9, tap = rem - c * 9;
    wT[(c * 9 + tap) * CIN + o] = w[i];
}

// ---------------- Kernel 3: transposed conv (stride 2, pad 1, out_pad 1) ----------------
// up[n,co,y,x] = sum_ci sum_{ky,kx : (y+1-ky) even, (x+1-kx) even} x[n,ci,(y+1-ky)/2,(x+1-kx)/2] * w[ci,co,ky,kx]
// y even -> ky=1 ; y odd -> ky=2 (always valid) and ky=0 (iy=(y+1)/2, invalid at y=127).
// x even=2t -> kx=1 (ix=t) ; x odd=2t+1 -> kx=0 (ix=t+1), kx=2 (ix=t).
// grid (2 co-halves, 128 y, 2 n), block 256 = 16 xg * 16 cg ; thread: 4 co x 4 x-pairs (8 outputs).
__global__ __launch_bounds__(256) void k_tconv(const float* __restrict__ x,
                                               const float* __restrict__ w,
                                               float* __restrict__ up) {
    int tid = threadIdx.x;
    int xg = tid & 15;
    int cg = tid >> 4;
    int half = blockIdx.x;
    int y = blockIdx.y;
    int n = blockIdx.z;
    int co0 = half * 64 + cg * 4;
    int t0 = xg * 4;

    int ky0, iy0, ky1 = 0, iy1 = 0, nky;
    if ((y & 1) == 0) { ky0 = 1; iy0 = y >> 1; nky = 1; }
    else {
        ky0 = 2; iy0 = (y - 1) >> 1; nky = 1;
        int iyt = (y + 1) >> 1;
        if (iyt < H0) { ky1 = 0; iy1 = iyt; nky = 2; }
    }

    float acc[4][8];
#pragma unroll
    for (int j = 0; j < 4; ++j)
#pragma unroll
        for (int p = 0; p < 8; ++p) acc[j][p] = 0.f;

    const float* xn = x + n * CIN * H0 * W0;
    for (int ci = 0; ci < CIN; ++ci) {
        const float* xr = xn + ci * H0 * W0;
#pragma unroll
        for (int s = 0; s < 2; ++s) {
            if (s == 1 && nky < 2) break;
            int ky = (s == 0) ? ky0 : ky1;
            int iy = (s == 0) ? iy0 : iy1;
            const float* xrow = xr + iy * W0;
            float xv[5];
#pragma unroll
            for (int u = 0; u < 5; ++u) {
                int ix = t0 + u;
                xv[u] = (ix < W0) ? xrow[ix] : 0.f;
            }
#pragma unroll
            for (int j = 0; j < 4; ++j) {
                const float* wp = w + ((ci * COUT) + co0 + j) * 9 + ky * 3;
                float wa = wp[0], wb = wp[1], wc = wp[2];
#pragma unroll
                for (int u = 0; u < 4; ++u) {
                    acc[j][2 * u]     += xv[u] * wb;                  // even x
                    acc[j][2 * u + 1] += xv[u + 1] * wa + xv[u] * wc; // odd x
                }
            }
        }
    }
#pragma unroll
    for (int j = 0; j < 4; ++j) {
        float* op = up + (((n * COUT) + co0 + j) * HU + y) * WU + 2 * t0;
#pragma unroll
        for (int u = 0; u < 4; ++u)
            *(float2*)(op + 2 * u) = make_float2(acc[j][2 * u], acc[j][2 * u + 1]);
    }
}

// ---------------- Kernel 4: deformable conv with uniform offsets ----------------
// out[n,o,y,x] = sum_c sum_tap w[o,c,tap] * bilin(up[n,c], y+iy[tap]+{0,1}, x+ix[tap]+{0,1})
// grid (64 spatial tiles 16x16, 4 o-chunks of 64, 2 n), block 256.
// thread = (og 0..7)*(pg 0..31): owns 8 o x 8 consecutive x in one row.
__global__ __launch_bounds__(256) void k_deform(const float* __restrict__ up,
                                                const float* __restrict__ wT,
                                                const int* __restrict__ ipar,
                                                const float* __restrict__ fpar,
                                                float* __restrict__ out) {
    __shared__ __align__(16) float U[8][20][21];   // c-chunk x (16+2halo*2) rows, stride 21 vs conflicts
    __shared__ __align__(16) float Wt[8][9][64];   // [c][tap][o]

    int tid = threadIdx.x;
    int og = tid >> 5;          // 0..7  -> o sub-block of 8
    int pg = tid & 31;          // 0..31
    int row = pg >> 1;          // 0..15
    int ch  = pg & 1;           // 0/1
    int xloc = ch * 8;

    int tileid = blockIdx.x;
    int tx0 = (tileid & 7) * 16;
    int ty0 = (tileid >> 3) * 16;
    int oc = blockIdx.y;
    int n  = blockIdx.z;

    int iyA[9], ixA[9];
    float wy0A[9], wy1A[9], wx0A[9], wx1A[9];
#pragma unroll
    for (int tap = 0; tap < 9; ++tap) {
        iyA[tap] = ipar[(n * 9 + tap) * 2 + 0];
        ixA[tap] = ipar[(n * 9 + tap) * 2 + 1];
        float fy = fpar[(n * 9 + tap) * 2 + 0];
        float fx = fpar[(n * 9 + tap) * 2 + 1];
        wy1A[tap] = fy; wy0A[tap] = 1.f - fy;
        wx1A[tap] = fx; wx0A[tap] = 1.f - fx;
    }

    float acc[8][8];
#pragma unroll
    for (int os = 0; os < 8; ++os)
#pragma unroll
        for (int p = 0; p < 8; ++p) acc[os][p] = 0.f;

    const float* upn = up + n * COUT * HU * WU;

    for (int cc = 0; cc < COUT; cc += 8) {
        __syncthreads();
        // stage up tile (zero-padded halo of 2)
        for (int i = tid; i < 8 * 20 * 20; i += 256) {
            int c = i / 400, r = (i % 400) / 20, col = i % 20;
            int gy = ty0 + r - 2, gx = tx0 + col - 2;
            float v = 0.f;
            if (gy >= 0 && gy < HU && gx >= 0 && gx < WU)
                v = upn[(cc + c) * HU * WU + gy * WU + gx];
            U[c][r][col] = v;
        }
        // stage weights (coalesced: o fastest in both global and LDS)
        for (int i = tid; i < 8 * 9 * 64; i += 256) {
            int c = i / 576, rem = i % 576, tap = rem / 64, o = rem - tap * 64;
            Wt[c][tap][o] = wT[((cc + c) * 9 + tap) * CIN + oc * 64 + o];
        }
        __syncthreads();

#pragma unroll 1
        for (int c = 0; c < 8; ++c) {
#pragma unroll
            for (int tap = 0; tap < 9; ++tap) {
                int yy = row + 2 + iyA[tap];
                int xx = xloc + 2 + ixA[tap];
                float t0v[9];
#pragma unroll
                for (int j2 = 0; j2 < 9; ++j2)
                    t0v[j2] = wy0A[tap] * U[c][yy][xx + j2] + wy1A[tap] * U[c][yy + 1][xx + j2];
                float sv[8];
#pragma unroll
                for (int p = 0; p < 8; ++p)
                    sv[p] = wx0A[tap] * t0v[p] + wx1A[tap] * t0v[p + 1];
                float4 wa = *(float4*)&Wt[c][tap][og * 8];
                float4 wb = *(float4*)&Wt[c][tap][og * 8 + 4];
                float wv[8] = {wa.x, wa.y, wa.z, wa.w, wb.x, wb.y, wb.z, wb.w};
#pragma unroll
                for (int os = 0; os < 8; ++os)
#pragma unroll
                    for (int p = 0; p < 8; ++p)
                        acc[os][p] += wv[os] * sv[p];
            }
        }
    }

    int y = ty0 + row;
#pragma unroll
    for (int os = 0; os < 8; ++os) {
        int o = oc * 64 + og * 8 + os;
        float* op = out + (((n * CIN) + o) * HU + y) * WU + tx0 + xloc;
        *(float4*)(op)     = make_float4(acc[os][0], acc[os][1], acc[os][2], acc[os][3]);
        *(float4*)(op + 4) = make_float4(acc[os][4], acc[os][5], acc[os][6], acc[os][7]);
    }
}

extern "C" void kernel_launch(void* const* d_in, const int* in_sizes, int n_in,
                              void* d_out, int out_size, void* d_ws, size_t ws_size,
                              hipStream_t stream) {
    const float* x   = (const float*)d_in[0];
    const float* lat = (const float*)d_in[1];
    const float* tw  = (const float*)d_in[2];
    const float* w1  = (const float*)d_in[3];
    const float* b1  = (const float*)d_in[4];
    const float* w2  = (const float*)d_in[5];
    const float* b2  = (const float*)d_in[6];
    float* out = (float*)d_out;

    char* ws = (char*)d_ws;
    float* up   = (float*)ws;                       // 2*128*128*128*4 = 16,777,216 B
    float* wT   = (float*)(ws + 16777216);          // 294912*4 = 1,179,648 B
    int*   ipar = (int*)(ws + 17956864);            // 36 ints
    float* fpar = (float*)(ws + 17957008);          // 36 floats

    k_offset<<<1, 128, 0, stream>>>(lat, w1, b1, w2, b2, ipar, fpar);
    k_wtrans<<<1152, 256, 0, stream>>>(tw, wT);
    k_tconv<<<dim3(2, 128, 2), 256, 0, stream>>>(x, tw, up);
    k_deform<<<dim3(64, 4, 2), 256, 0, stream>>>(up, wT, ipar, fpar, out);
}

// Round 2
// 200.952 us; speedup vs baseline: 4.7718x; 4.7718x over previous
//
#include <hip/hip_runtime.h>
#include <math.h>

#define CIN 256
#define COUT 128
#define H0 64
#define W0 64
#define HU 128
#define WU 128
#define NB 2

typedef __attribute__((ext_vector_type(8))) short s16x8;
typedef __attribute__((ext_vector_type(4))) float f32x4;

__device__ __forceinline__ unsigned short f2bf(float f) {
    union { float f; unsigned int u; } v; v.f = f;
    unsigned int u = v.u + 0x7FFFu + ((v.u >> 16) & 1u);
    return (unsigned short)(u >> 16);
}

// ---------------- Kernel 1: offset network + bilinear params (verified R1) ----------------
__global__ void k_offset(const float* __restrict__ lat,
                         const float* __restrict__ w1, const float* __restrict__ b1,
                         const float* __restrict__ w2, const float* __restrict__ b2,
                         int* __restrict__ ipar, float* __restrict__ fpar) {
    __shared__ float h[NB][64];
    __shared__ float offv[NB][18];
    int t = threadIdx.x;
    if (t < NB * 64) {
        int n = t >> 6, o = t & 63;
        float s = b1[o];
        const float* ln = lat + n * COUT;
        for (int c = 0; c < COUT; ++c) s += ln[c] * w1[(o * COUT + c) * 9 + 4];
        h[n][o] = fmaxf(s, 0.f);
    }
    __syncthreads();
    if (t < NB * 18) {
        int n = t / 18, j = t % 18;
        float s = b2[j];
        for (int o = 0; o < 64; ++o) s += h[n][o] * w2[(j * 64 + o) * 9 + 4];
        float ov = tanhf(s);
        ov = fminf(fmaxf(ov, -0.999999f), 0.999999f);
        offv[n][j] = ov;
    }
    __syncthreads();
    if (t < NB * 18) {
        int n = t / 18, j = t % 18;
        int tap = j >> 1, d = j & 1;
        float ov = offv[n][j];
        float fl = floorf(ov);
        int kc = d ? (tap % 3) : (tap / 3);
        ipar[(n * 9 + tap) * 2 + d] = kc - 1 + (int)fl;
        fpar[(n * 9 + tap) * 2 + d] = ov - fl;
    }
}

// ---------------- Kernel 2: weight prep (bf16, GEMM layouts) ----------------
// A2[o][tap*128+c]        = trans_w[o][c][tap]                (deform GEMM A)
// Aw[co][(ky*3+kx)*256+ci] = trans_w[ci][co][2-ky][2-kx]      (tconv GEMM A)
__global__ void k_prep_w(const float* __restrict__ tw,
                         unsigned short* __restrict__ A2,
                         unsigned short* __restrict__ Aw) {
    int i = blockIdx.x * 256 + threadIdx.x;
    const int NA = 256 * 1152;
    if (i < NA) {
        int o = i / 1152, k = i - o * 1152;
        int tap = k >> 7, c = k & 127;
        A2[i] = f2bf(tw[(o * 128 + c) * 9 + tap]);
    } else {
        int j = i - NA;
        if (j < 128 * 2304) {
            int co = j / 2304, k = j - co * 2304;
            int t9 = k >> 8, ci = k & 255;
            int ky = t9 / 3, kx = t9 - ky * 3;
            Aw[j] = f2bf(tw[(ci * 128 + co) * 9 + (2 - ky) * 3 + (2 - kx)]);
        }
    }
}

// ---------------- Kernel 3: x -> channels-last padded xp[n][65][65][256] ----------------
// real data at [0..63][0..63]; row/col 64 stay zero (memset).
__global__ __launch_bounds__(256) void k_prep_x(const float* __restrict__ x,
                                                float* __restrict__ xp) {
    __shared__ float T[64][65];
    int t = threadIdx.x;
    int h = blockIdx.x;
    int c0 = blockIdx.y * 64;
    int n = blockIdx.z;
    {
        int wcol = t & 63, sub = t >> 6;
        for (int r = 0; r < 16; ++r) {
            int ci_l = r * 4 + sub;
            T[ci_l][wcol] = x[((n * 256 + c0 + ci_l) * 64 + h) * 64 + wcol];
        }
    }
    __syncthreads();
    int wcol = t >> 2, cg = t & 3;
    float* dst = xp + (size_t)n * (65 * 65 * 256) + (h * 65 + wcol) * 256 + c0;
    for (int j = 0; j < 4; ++j) {
        int ci_l = cg * 16 + j * 4;
        float4 v = make_float4(T[ci_l][wcol], T[ci_l + 1][wcol], T[ci_l + 2][wcol], T[ci_l + 3][wcol]);
        *(float4*)(dst + ci_l) = v;
    }
}

// ---------------- Kernel 4: transposed conv as bf16 MFMA implicit GEMM ----------------
// up[n,co,y,x] = sum_{ci,ky,kx} dilx[y+ky-1][x+kx-1] * w[ci,co,2-ky,2-kx]
// dilx[d][c2] = (d,c2 even) ? x[d/2][c2/2] : 0 ; odd-d K-chunks skipped entirely.
// Block: M=128 co x N=64 x-positions (one y row). Writes upp channels-last fp32.
__global__ __launch_bounds__(256) void k_tconv_mfma(const float* __restrict__ xp,
                                                    const unsigned short* __restrict__ Aw,
                                                    float* __restrict__ upp) {
    __shared__ unsigned short As[128][40];
    __shared__ unsigned short Bs[64][40];
    int t = threadIdx.x;
    int tx0 = blockIdx.x * 64;
    int y = blockIdx.y;
    int n = blockIdx.z;
    const float* xpn = xp + (size_t)n * (65 * 65 * 256);

    int lane = t & 63, w = t >> 6;
    int col = lane & 15, q = lane >> 4;
    int wm = w >> 1, wn = w & 1;

    f32x4 acc[4][2];
#pragma unroll
    for (int mi = 0; mi < 4; ++mi)
#pragma unroll
        for (int ni = 0; ni < 2; ++ni) acc[mi][ni] = (f32x4){0.f, 0.f, 0.f, 0.f};

    int bx = t >> 2, bcg = t & 3;

    for (int ky = 0; ky < 3; ++ky) {
        int d = y + ky - 1;
        if (d & 1) continue;          // also skips d == -1
        int d2 = d >> 1;              // 0..64 (row 64 is zero pad)
        for (int kx = 0; kx < 3; ++kx) {
            for (int cb = 0; cb < 8; ++cb) {
                __syncthreads();
                int kc = (ky * 3 + kx) * 256 + cb * 32;
#pragma unroll
                for (int it = 0; it < 2; ++it) {
                    int gid = it * 256 + t;
                    int row = gid >> 2, cg = gid & 3;
                    *(uint4*)&As[row][cg * 8] = *(const uint4*)(Aw + row * 2304 + kc + cg * 8);
                }
                {
                    int c2 = tx0 + bx + kx - 1;
                    uint4 pk = make_uint4(0u, 0u, 0u, 0u);
                    if (!(c2 & 1)) {  // c2==-1 is odd; c2==128 -> col 64 zeros
                        const float* p = xpn + (d2 * 65 + (c2 >> 1)) * 256 + cb * 32 + bcg * 8;
                        float4 v0 = *(const float4*)p;
                        float4 v1 = *(const float4*)(p + 4);
                        pk.x = f2bf(v0.x) | ((unsigned)f2bf(v0.y) << 16);
                        pk.y = f2bf(v0.z) | ((unsigned)f2bf(v0.w) << 16);
                        pk.z = f2bf(v1.x) | ((unsigned)f2bf(v1.y) << 16);
                        pk.w = f2bf(v1.z) | ((unsigned)f2bf(v1.w) << 16);
                    }
                    *(uint4*)&Bs[bx][bcg * 8] = pk;
                }
                __syncthreads();
                s16x8 a[4], b[2];
#pragma unroll
                for (int mi = 0; mi < 4; ++mi)
                    a[mi] = *(const s16x8*)&As[wm * 64 + mi * 16 + col][q * 8];
#pragma unroll
                for (int ni = 0; ni < 2; ++ni)
                    b[ni] = *(const s16x8*)&Bs[wn * 32 + ni * 16 + col][q * 8];
#pragma unroll
                for (int mi = 0; mi < 4; ++mi)
#pragma unroll
                    for (int ni = 0; ni < 2; ++ni)
                        acc[mi][ni] = __builtin_amdgcn_mfma_f32_16x16x32_bf16(a[mi], b[ni], acc[mi][ni], 0, 0, 0);
            }
        }
    }
    float* uppn = upp + (size_t)n * (132 * 132 * 128);
#pragma unroll
    for (int mi = 0; mi < 4; ++mi)
#pragma unroll
        for (int ni = 0; ni < 2; ++ni) {
            int co = wm * 64 + mi * 16 + q * 4;
            int xg = tx0 + wn * 32 + ni * 16 + col;
            float* p = uppn + ((y + 2) * 132 + (xg + 2)) * 128 + co;
            *(float4*)p = *(float4*)&acc[mi][ni];
        }
}

// ---------------- Kernel 5: deformable conv as bf16 MFMA GEMM, fused bilinear B-staging ----
// out[n][o][y][x] = sum_{tap,c} A2[o][tap*128+c] * bilin(upp[n], y,x,tap,c)
// Block: M=256 (all o) x N=64 x-positions (one y row); K=1152, BK=32 (fixed tap per chunk).
__global__ __launch_bounds__(256) void k_deform_mfma(const float* __restrict__ upp,
                                                     const unsigned short* __restrict__ A2,
                                                     const int* __restrict__ ipar,
                                                     const float* __restrict__ fpar,
                                                     float* __restrict__ out) {
    __shared__ unsigned short As[256][40];
    __shared__ unsigned short Bs[64][40];
    int t = threadIdx.x;
    int tx0 = blockIdx.x * 64;
    int y = blockIdx.y;
    int n = blockIdx.z;
    const float* uppn = upp + (size_t)n * (132 * 132 * 128);

    int lane = t & 63, w = t >> 6;
    int col = lane & 15, q = lane >> 4;

    f32x4 acc[4][4];
#pragma unroll
    for (int mi = 0; mi < 4; ++mi)
#pragma unroll
        for (int ni = 0; ni < 4; ++ni) acc[mi][ni] = (f32x4){0.f, 0.f, 0.f, 0.f};

    int bx = t >> 2, bcg = t & 3;

    for (int tap = 0; tap < 9; ++tap) {
        int iy = ipar[(n * 9 + tap) * 2 + 0];
        int ix = ipar[(n * 9 + tap) * 2 + 1];
        float fy = fpar[(n * 9 + tap) * 2 + 0];
        float fx = fpar[(n * 9 + tap) * 2 + 1];
        float wy0 = 1.f - fy, wy1 = fy, wx0 = 1.f - fx, wx1 = fx;
        int y2 = y + 2 + iy;                    // 0..130 (always in-bounds w/ halo)
        const float* rowp = uppn + ((y2 * 132) + (tx0 + 2 + ix + bx)) * 128 + bcg * 8;
        for (int cb = 0; cb < 128; cb += 32) {
            __syncthreads();
            int kb = tap * 128 + cb;
#pragma unroll
            for (int it = 0; it < 4; ++it) {
                int gid = it * 256 + t;
                int row = gid >> 2, cg = gid & 3;
                *(uint4*)&As[row][cg * 8] = *(const uint4*)(A2 + row * 1152 + kb + cg * 8);
            }
            {
                const float* p = rowp + cb;
                float4 A0 = *(const float4*)p,           A1 = *(const float4*)(p + 4);
                float4 B0 = *(const float4*)(p + 128),   B1 = *(const float4*)(p + 132);
                float4 C0 = *(const float4*)(p + 16896), C1 = *(const float4*)(p + 16900);
                float4 D0 = *(const float4*)(p + 17024), D1 = *(const float4*)(p + 17028);
#define BL(Aa, Bb, Cc, Dd) (wy0 * (wx0 * (Aa) + wx1 * (Bb)) + wy1 * (wx0 * (Cc) + wx1 * (Dd)))
                float o0 = BL(A0.x, B0.x, C0.x, D0.x);
                float o1 = BL(A0.y, B0.y, C0.y, D0.y);
                float o2 = BL(A0.z, B0.z, C0.z, D0.z);
                float o3 = BL(A0.w, B0.w, C0.w, D0.w);
                float o4 = BL(A1.x, B1.x, C1.x, D1.x);
                float o5 = BL(A1.y, B1.y, C1.y, D1.y);
                float o6 = BL(A1.z, B1.z, C1.z, D1.z);
                float o7 = BL(A1.w, B1.w, C1.w, D1.w);
#undef BL
                uint4 pk;
                pk.x = f2bf(o0) | ((unsigned)f2bf(o1) << 16);
                pk.y = f2bf(o2) | ((unsigned)f2bf(o3) << 16);
                pk.z = f2bf(o4) | ((unsigned)f2bf(o5) << 16);
                pk.w = f2bf(o6) | ((unsigned)f2bf(o7) << 16);
                *(uint4*)&Bs[bx][bcg * 8] = pk;
            }
            __syncthreads();
            s16x8 a[4], b[4];
#pragma unroll
            for (int mi = 0; mi < 4; ++mi)
                a[mi] = *(const s16x8*)&As[w * 64 + mi * 16 + col][q * 8];
#pragma unroll
            for (int ni = 0; ni < 4; ++ni)
                b[ni] = *(const s16x8*)&Bs[ni * 16 + col][q * 8];
#pragma unroll
            for (int mi = 0; mi < 4; ++mi)
#pragma unroll
                for (int ni = 0; ni < 4; ++ni)
                    acc[mi][ni] = __builtin_amdgcn_mfma_f32_16x16x32_bf16(a[mi], b[ni], acc[mi][ni], 0, 0, 0);
        }
    }
#pragma unroll
    for (int mi = 0; mi < 4; ++mi)
#pragma unroll
        for (int ni = 0; ni < 4; ++ni) {
            int o = w * 64 + mi * 16 + q * 4;
            int xg = tx0 + ni * 16 + col;
            float* p = out + (((size_t)(n * 256 + o)) * 128 + y) * 128 + xg;
            p[0]         = acc[mi][ni][0];
            p[16384]     = acc[mi][ni][1];
            p[2 * 16384] = acc[mi][ni][2];
            p[3 * 16384] = acc[mi][ni][3];
        }
}

extern "C" void kernel_launch(void* const* d_in, const int* in_sizes, int n_in,
                              void* d_out, int out_size, void* d_ws, size_t ws_size,
                              hipStream_t stream) {
    const float* x   = (const float*)d_in[0];
    const float* lat = (const float*)d_in[1];
    const float* tw  = (const float*)d_in[2];
    const float* w1  = (const float*)d_in[3];
    const float* b1  = (const float*)d_in[4];
    const float* w2  = (const float*)d_in[5];
    const float* b2  = (const float*)d_in[6];
    float* out = (float*)d_out;

    char* ws = (char*)d_ws;
    // upp: 2 * 132*132*128 fp32 (channels-last, halo 2)   = 17,842,176 B @ 0
    // xp : 2 * 65*65*256  fp32 (channels-last, +1 zero)   =  8,652,800 B @ 17,842,176
    // A2 : 256*1152 bf16                                  =    589,824 B @ 26,494,976
    // Aw : 128*2304 bf16                                  =    589,824 B @ 27,084,800
    float* upp          = (float*)ws;
    float* xp           = (float*)(ws + 17842176);
    unsigned short* A2  = (unsigned short*)(ws + 26494976);
    unsigned short* Aw  = (unsigned short*)(ws + 27084800);
    int*   ipar         = (int*)(ws + 27674624);
    float* fpar         = (float*)(ws + 27674768);

    hipMemsetAsync(upp, 0, 17842176, stream);
    hipMemsetAsync(xp, 0, 8652800, stream);

    k_offset<<<1, 128, 0, stream>>>(lat, w1, b1, w2, b2, ipar, fpar);
    k_prep_w<<<2304, 256, 0, stream>>>(tw, A2, Aw);
    k_prep_x<<<dim3(64, 4, 2), 256, 0, stream>>>(x, xp);
    k_tconv_mfma<<<dim3(2, 128, 2), 256, 0, stream>>>(xp, Aw, upp);
    k_deform_mfma<<<dim3(2, 128, 2), 256, 0, stream>>>(upp, A2, ipar, fpar, out);
}

// Round 3
// 160.876 us; speedup vs baseline: 5.9605x; 1.2491x over previous
//
#include <hip/hip_runtime.h>
#include <hip/hip_bf16.h>
#include <math.h>

#define CIN 256
#define COUT 128
#define NB 2

typedef __attribute__((ext_vector_type(8))) short s16x8;
typedef __attribute__((ext_vector_type(4))) float f32x4;

__device__ __forceinline__ unsigned short f2bf(float f) {
    union { float f; unsigned int u; } v; v.f = f;
    unsigned int u = v.u + 0x7FFFu + ((v.u >> 16) & 1u);
    return (unsigned short)(u >> 16);
}
__device__ __forceinline__ unsigned pk2(float lo, float hi) {
    __hip_bfloat162 h = __float22bfloat162_rn(make_float2(lo, hi));
    union { __hip_bfloat162 h; unsigned u; } v; v.h = h;
    return v.u;
}
__device__ __forceinline__ float blo(unsigned u) {
    union { unsigned u; float f; } v; v.u = u << 16; return v.f;
}
__device__ __forceinline__ float bhi(unsigned u) {
    union { unsigned u; float f; } v; v.u = u & 0xffff0000u; return v.f;
}

// ---------------- Kernel 1: offset net (LDS-staged weights) + bilinear params ----------------
__global__ __launch_bounds__(256) void k_offset(const float* __restrict__ lat,
                         const float* __restrict__ w1, const float* __restrict__ b1,
                         const float* __restrict__ w2, const float* __restrict__ b2,
                         int* __restrict__ ipar, float* __restrict__ fpar) {
    __shared__ float w1c[64][129];   // padded vs bank conflicts
    __shared__ float h[NB][64];
    __shared__ float offv[NB][18];
    int t = threadIdx.x;
    for (int i = t; i < 8192; i += 256) w1c[i >> 7][i & 127] = w1[i * 9 + 4];
    __syncthreads();
    if (t < NB * 64) {
        int n = t >> 6, o = t & 63;
        float s = b1[o];
        const float* ln = lat + n * COUT;
#pragma unroll 8
        for (int c = 0; c < COUT; ++c) s += ln[c] * w1c[o][c];
        h[n][o] = fmaxf(s, 0.f);
    }
    __syncthreads();
    if (t < NB * 18) {
        int n = t / 18, j = t % 18;
        float s = b2[j];
        for (int o = 0; o < 64; ++o) s += h[n][o] * w2[(j * 64 + o) * 9 + 4];
        float ov = tanhf(s);
        ov = fminf(fmaxf(ov, -0.999999f), 0.999999f);
        offv[n][j] = ov;
    }
    __syncthreads();
    if (t < NB * 18) {
        int n = t / 18, j = t % 18;
        int tap = j >> 1, d = j & 1;
        float ov = offv[n][j];
        float fl = floorf(ov);
        int kc = d ? (tap % 3) : (tap / 3);
        ipar[(n * 9 + tap) * 2 + d] = kc - 1 + (int)fl;
        fpar[(n * 9 + tap) * 2 + d] = ov - fl;
    }
}

// ---------------- Kernel 2: weight prep (bf16, GEMM layouts) ----------------
// A2[o][tap*128+c]         = trans_w[o][c][tap]              (deform GEMM A)
// Aw[co][(ky*3+kx)*256+ci] = trans_w[ci][co][2-ky][2-kx]     (tconv GEMM A)
__global__ void k_prep_w(const float* __restrict__ tw,
                         unsigned short* __restrict__ A2,
                         unsigned short* __restrict__ Aw) {
    int i = blockIdx.x * 256 + threadIdx.x;
    const int NA = 256 * 1152;
    if (i < NA) {
        int o = i / 1152, k = i - o * 1152;
        int tap = k >> 7, c = k & 127;
        A2[i] = f2bf(tw[(o * 128 + c) * 9 + tap]);
    } else {
        int j = i - NA;
        if (j < 128 * 2304) {
            int co = j / 2304, k = j - co * 2304;
            int t9 = k >> 8, ci = k & 255;
            int ky = t9 / 3, kx = t9 - ky * 3;
            Aw[j] = f2bf(tw[(ci * 128 + co) * 9 + (2 - ky) * 3 + (2 - kx)]);
        }
    }
}

// ---------------- Kernel 3: x -> channels-last padded bf16 xp[n][65][65][256] ----------------
__global__ __launch_bounds__(256) void k_prep_x(const float* __restrict__ x,
                                                unsigned short* __restrict__ xp) {
    __shared__ float T[64][65];
    int t = threadIdx.x;
    int h = blockIdx.x;
    int c0 = blockIdx.y * 64;
    int n = blockIdx.z;
    {
        int wcol = t & 63, sub = t >> 6;
        for (int r = 0; r < 16; ++r) {
            int ci_l = r * 4 + sub;
            T[ci_l][wcol] = x[((n * 256 + c0 + ci_l) * 64 + h) * 64 + wcol];
        }
    }
    __syncthreads();
    int wcol = t >> 2, cg = t & 3;
    unsigned short* dst = xp + (size_t)n * (65 * 65 * 256) + (h * 65 + wcol) * 256 + c0 + cg * 16;
    unsigned pk[8];
#pragma unroll
    for (int j = 0; j < 8; ++j)
        pk[j] = pk2(T[cg * 16 + 2 * j][wcol], T[cg * 16 + 2 * j + 1][wcol]);
    *(uint4*)dst = make_uint4(pk[0], pk[1], pk[2], pk[3]);
    *(uint4*)(dst + 8) = make_uint4(pk[4], pk[5], pk[6], pk[7]);
}

// ---------------- Kernel 4: tconv, parity-decomposed dense MFMA GEMM ----------------
// out x = 2*bx + xpar, y parity = phase. Valid (ky,kx): ky set by y-parity, kx by x-parity.
// B[p][ci] = xp[n][d2][p+s][ci]  (pure copy, zero-padding rows/cols handle bounds).
__global__ __launch_bounds__(256) void k_tconv2(const unsigned short* __restrict__ xp,
                                                const unsigned short* __restrict__ Aw,
                                                unsigned short* __restrict__ upp) {
    __shared__ unsigned short As[128][40];
    __shared__ unsigned short Bs[64][40];
    int t = threadIdx.x;
    int b = blockIdx.x;
    int phase = b >> 8, j = b & 255;
    int n = j >> 7, xpar = ((j >> 6) & 1) ^ phase, yh = j & 63;
    int y = yh * 2 + phase;
    const unsigned short* xpn = xp + (size_t)n * (65 * 65 * 256);

    int lane = t & 63, w = t >> 6;
    int col = lane & 15, q = lane >> 4;
    int wm = w >> 1, wn = w & 1;
    int bx = t >> 2, bcg = t & 3;

    f32x4 acc[4][2];
#pragma unroll
    for (int mi = 0; mi < 4; ++mi)
#pragma unroll
        for (int ni = 0; ni < 2; ++ni) acc[mi][ni] = (f32x4){0.f, 0.f, 0.f, 0.f};

    int kys[2], kxs[2], nky, nkx;
    if (phase) { kys[0] = 0; kys[1] = 2; nky = 2; } else { kys[0] = 1; nky = 1; }
    if (xpar)  { kxs[0] = 0; kxs[1] = 2; nkx = 2; } else { kxs[0] = 1; nkx = 1; }

    for (int a1 = 0; a1 < nky; ++a1) {
        int ky = kys[a1];
        int d2 = (y + ky - 1) >> 1;               // 0..64 (64 = zero row)
        for (int a2 = 0; a2 < nkx; ++a2) {
            int kx = kxs[a2];
            int s = (xpar + kx - 1) >> 1;         // 0 or 1
            const unsigned short* brow = xpn + ((d2 * 65) + s + bx) * 256 + bcg * 8;
            int t9 = ky * 3 + kx;
            for (int cb = 0; cb < 256; cb += 32) {
                __syncthreads();
#pragma unroll
                for (int it = 0; it < 2; ++it) {
                    int gid = it * 256 + t;
                    int row = gid >> 2, cg = gid & 3;
                    *(uint4*)&As[row][cg * 8] = *(const uint4*)(Aw + row * 2304 + t9 * 256 + cb + cg * 8);
                }
                *(uint4*)&Bs[bx][bcg * 8] = *(const uint4*)(brow + cb);
                __syncthreads();
                s16x8 a[4], bb[2];
#pragma unroll
                for (int mi = 0; mi < 4; ++mi)
                    a[mi] = *(const s16x8*)&As[wm * 64 + mi * 16 + col][q * 8];
#pragma unroll
                for (int ni = 0; ni < 2; ++ni)
                    bb[ni] = *(const s16x8*)&Bs[wn * 32 + ni * 16 + col][q * 8];
#pragma unroll
                for (int mi = 0; mi < 4; ++mi)
#pragma unroll
                    for (int ni = 0; ni < 2; ++ni)
                        acc[mi][ni] = __builtin_amdgcn_mfma_f32_16x16x32_bf16(a[mi], bb[ni], acc[mi][ni], 0, 0, 0);
            }
        }
    }
    unsigned short* uppn = upp + (size_t)n * (132 * 132 * 128);
#pragma unroll
    for (int mi = 0; mi < 4; ++mi)
#pragma unroll
        for (int ni = 0; ni < 2; ++ni) {
            int co = wm * 64 + mi * 16 + q * 4;
            int p64 = wn * 32 + ni * 16 + col;
            int xg = 2 * p64 + xpar;
            unsigned short* p = uppn + ((y + 2) * 132 + (xg + 2)) * 128 + co;
            unsigned lo = pk2(acc[mi][ni][0], acc[mi][ni][1]);
            unsigned hi = pk2(acc[mi][ni][2], acc[mi][ni][3]);
            *(uint2*)p = make_uint2(lo, hi);
        }
}

// ---------------- Kernel 5: deform conv MFMA GEMM, bf16 upp, XCD-band swizzle ----------------
__global__ __launch_bounds__(256) void k_deform2(const unsigned short* __restrict__ upp,
                                                 const unsigned short* __restrict__ A2,
                                                 const int* __restrict__ ipar,
                                                 const float* __restrict__ fpar,
                                                 float* __restrict__ out) {
    __shared__ unsigned short As[256][40];
    __shared__ unsigned short Bs[64][40];
    int t = threadIdx.x;
    int b = blockIdx.x;
    // XCD-band swizzle: XCD (b&7) owns a contiguous 32-row y band of one n.
    int xcd = b & 7, j = b >> 3;
    int n = xcd >> 2, band = xcd & 3;
    int y = band * 32 + (j & 31);
    int tx0 = (j >> 5) * 64;
    const unsigned short* uppn = upp + (size_t)n * (132 * 132 * 128);

    int lane = t & 63, w = t >> 6;
    int col = lane & 15, q = lane >> 4;
    int bx = t >> 2, bcg = t & 3;

    int iyA[9], ixA[9];
    float w00[9], w01[9], w10[9], w11[9];
#pragma unroll
    for (int tap = 0; tap < 9; ++tap) {
        iyA[tap] = ipar[(n * 9 + tap) * 2 + 0];
        ixA[tap] = ipar[(n * 9 + tap) * 2 + 1];
        float fy = fpar[(n * 9 + tap) * 2 + 0];
        float fx = fpar[(n * 9 + tap) * 2 + 1];
        w00[tap] = (1.f - fy) * (1.f - fx);
        w01[tap] = (1.f - fy) * fx;
        w10[tap] = fy * (1.f - fx);
        w11[tap] = fy * fx;
    }

    f32x4 acc[4][4];
#pragma unroll
    for (int mi = 0; mi < 4; ++mi)
#pragma unroll
        for (int ni = 0; ni < 4; ++ni) acc[mi][ni] = (f32x4){0.f, 0.f, 0.f, 0.f};

    for (int tap = 0; tap < 9; ++tap) {
        int y2 = y + 2 + iyA[tap];
        const unsigned short* rowp = uppn + ((y2 * 132) + (tx0 + 2 + ixA[tap] + bx)) * 128 + bcg * 8;
        float c00 = w00[tap], c01 = w01[tap], c10 = w10[tap], c11 = w11[tap];
        for (int cb = 0; cb < 128; cb += 32) {
            __syncthreads();
            int kb = tap * 128 + cb;
#pragma unroll
            for (int it = 0; it < 4; ++it) {
                int gid = it * 256 + t;
                int row = gid >> 2, cg = gid & 3;
                *(uint4*)&As[row][cg * 8] = *(const uint4*)(A2 + row * 1152 + kb + cg * 8);
            }
            {
                const unsigned short* p = rowp + cb;
                uint4 uA = *(const uint4*)p;
                uint4 uB = *(const uint4*)(p + 128);
                uint4 uC = *(const uint4*)(p + 16896);
                uint4 uD = *(const uint4*)(p + 17024);
                unsigned ua[4] = {uA.x, uA.y, uA.z, uA.w};
                unsigned ub[4] = {uB.x, uB.y, uB.z, uB.w};
                unsigned uc[4] = {uC.x, uC.y, uC.z, uC.w};
                unsigned ud[4] = {uD.x, uD.y, uD.z, uD.w};
                unsigned pk[4];
#pragma unroll
                for (int i = 0; i < 4; ++i) {
                    float vL = c00 * blo(ua[i]) + c01 * blo(ub[i]) + c10 * blo(uc[i]) + c11 * blo(ud[i]);
                    float vH = c00 * bhi(ua[i]) + c01 * bhi(ub[i]) + c10 * bhi(uc[i]) + c11 * bhi(ud[i]);
                    pk[i] = pk2(vL, vH);
                }
                *(uint4*)&Bs[bx][bcg * 8] = make_uint4(pk[0], pk[1], pk[2], pk[3]);
            }
            __syncthreads();
            s16x8 a[4], bb[4];
#pragma unroll
            for (int mi = 0; mi < 4; ++mi)
                a[mi] = *(const s16x8*)&As[w * 64 + mi * 16 + col][q * 8];
#pragma unroll
            for (int ni = 0; ni < 4; ++ni)
                bb[ni] = *(const s16x8*)&Bs[ni * 16 + col][q * 8];
#pragma unroll
            for (int mi = 0; mi < 4; ++mi)
#pragma unroll
                for (int ni = 0; ni < 4; ++ni)
                    acc[mi][ni] = __builtin_amdgcn_mfma_f32_16x16x32_bf16(a[mi], bb[ni], acc[mi][ni], 0, 0, 0);
        }
    }
#pragma unroll
    for (int mi = 0; mi < 4; ++mi)
#pragma unroll
        for (int ni = 0; ni < 4; ++ni) {
            int o = w * 64 + mi * 16 + q * 4;
            int xg = tx0 + ni * 16 + col;
            float* p = out + (((size_t)(n * 256 + o)) * 128 + y) * 128 + xg;
            p[0]         = acc[mi][ni][0];
            p[16384]     = acc[mi][ni][1];
            p[2 * 16384] = acc[mi][ni][2];
            p[3 * 16384] = acc[mi][ni][3];
        }
}

extern "C" void kernel_launch(void* const* d_in, const int* in_sizes, int n_in,
                              void* d_out, int out_size, void* d_ws, size_t ws_size,
                              hipStream_t stream) {
    const float* x   = (const float*)d_in[0];
    const float* lat = (const float*)d_in[1];
    const float* tw  = (const float*)d_in[2];
    const float* w1  = (const float*)d_in[3];
    const float* b1  = (const float*)d_in[4];
    const float* w2  = (const float*)d_in[5];
    const float* b2  = (const float*)d_in[6];
    float* out = (float*)d_out;

    char* ws = (char*)d_ws;
    // upp (bf16, halo 2): 2*132*132*128*2 = 8,921,088 B @ 0
    // xp  (bf16, +1 pad): 2*65*65*256*2   = 4,326,400 B @ 8,921,088
    // A2  : 256*1152*2 = 589,824 B @ 13,247,488
    // Aw  : 128*2304*2 = 589,824 B @ 13,837,312
    unsigned short* upp = (unsigned short*)ws;
    unsigned short* xp  = (unsigned short*)(ws + 8921088);
    unsigned short* A2  = (unsigned short*)(ws + 13247488);
    unsigned short* Aw  = (unsigned short*)(ws + 13837312);
    int*   ipar         = (int*)(ws + 14427136);
    float* fpar         = (float*)(ws + 14427280);

    hipMemsetAsync(upp, 0, 8921088, stream);
    hipMemsetAsync(xp, 0, 4326400, stream);

    k_offset<<<1, 256, 0, stream>>>(lat, w1, b1, w2, b2, ipar, fpar);
    k_prep_w<<<2304, 256, 0, stream>>>(tw, A2, Aw);
    k_prep_x<<<dim3(64, 4, 2), 256, 0, stream>>>(x, xp);
    k_tconv2<<<512, 256, 0, stream>>>(xp, Aw, upp);
    k_deform2<<<512, 256, 0, stream>>>(upp, A2, ipar, fpar, out);
}

// Round 4
// 150.409 us; speedup vs baseline: 6.3752x; 1.0696x over previous
//
#include <hip/hip_runtime.h>
#include <hip/hip_bf16.h>
#include <math.h>

typedef __attribute__((ext_vector_type(8))) short s16x8;
typedef __attribute__((ext_vector_type(4))) float f32x4;

__device__ __forceinline__ unsigned short f2bf(float f) {
    union { float f; unsigned int u; } v; v.f = f;
    unsigned int u = v.u + 0x7FFFu + ((v.u >> 16) & 1u);
    return (unsigned short)(u >> 16);
}
__device__ __forceinline__ unsigned pk2(float lo, float hi) {
    __hip_bfloat162 h = __float22bfloat162_rn(make_float2(lo, hi));
    union { __hip_bfloat162 h; unsigned u; } v; v.h = h;
    return v.u;
}
__device__ __forceinline__ float blo(unsigned u) {
    union { unsigned u; float f; } v; v.u = u << 16; return v.f;
}
__device__ __forceinline__ float bhi(unsigned u) {
    union { unsigned u; float f; } v; v.u = u & 0xffff0000u; return v.f;
}

// Blend 4 corner uint4s (8 bf16 channels each) into one packed uint4, store to LDS.
__device__ __forceinline__ void blend_store(uint4 uA, uint4 uB, uint4 uC, uint4 uD,
                                            float4 cw, unsigned short* dst) {
    unsigned ua[4] = {uA.x, uA.y, uA.z, uA.w};
    unsigned ub[4] = {uB.x, uB.y, uB.z, uB.w};
    unsigned uc[4] = {uC.x, uC.y, uC.z, uC.w};
    unsigned ud[4] = {uD.x, uD.y, uD.z, uD.w};
    unsigned pk[4];
#pragma unroll
    for (int i = 0; i < 4; ++i) {
        float vL = cw.x * blo(ua[i]) + cw.y * blo(ub[i]) + cw.z * blo(uc[i]) + cw.w * blo(ud[i]);
        float vH = cw.x * bhi(ua[i]) + cw.y * bhi(ub[i]) + cw.z * bhi(uc[i]) + cw.w * bhi(ud[i]);
        pk[i] = pk2(vL, vH);
    }
    *(uint4*)dst = make_uint4(pk[0], pk[1], pk[2], pk[3]);
}

// ============ Fused prep kernel (block-specialized) ============
// b==0          : offset net -> ipar/fpar
// b in [1,145)  : A2f  (deform A, MFMA-fragment order)  36864 slots
// b in [145,289): Awf  (tconv A, MFMA-fragment order)   36864 slots
// b in [289,801): xp   (x -> channels-last padded bf16)
__global__ __launch_bounds__(256) void k_prep(const float* __restrict__ x,
                                              const float* __restrict__ lat,
                                              const float* __restrict__ tw,
                                              const float* __restrict__ w1,
                                              const float* __restrict__ b1,
                                              const float* __restrict__ w2,
                                              const float* __restrict__ b2,
                                              unsigned short* __restrict__ xp,
                                              unsigned short* __restrict__ A2f,
                                              unsigned short* __restrict__ Awf,
                                              int* __restrict__ ipar,
                                              float* __restrict__ fpar) {
    __shared__ float sm[8420];
    int b = blockIdx.x, t = threadIdx.x;
    if (b == 0) {
        for (int i = t; i < 8192; i += 256) sm[(i >> 7) * 129 + (i & 127)] = w1[i * 9 + 4];
        __syncthreads();
        if (t < 128) {
            int n = t >> 6, o = t & 63;
            float s = b1[o];
            const float* ln = lat + n * 128;
#pragma unroll 8
            for (int c = 0; c < 128; ++c) s += ln[c] * sm[o * 129 + c];
            sm[8256 + t] = fmaxf(s, 0.f);
        }
        __syncthreads();
        if (t < 36) {
            int n = t / 18, j = t % 18;
            float s = b2[j];
            for (int o = 0; o < 64; ++o) s += sm[8256 + n * 64 + o] * w2[(j * 64 + o) * 9 + 4];
            float ov = tanhf(s);
            ov = fminf(fmaxf(ov, -0.999999f), 0.999999f);
            sm[8384 + t] = ov;
        }
        __syncthreads();
        if (t < 36) {
            int n = t / 18, j = t % 18;
            int tap = j >> 1, d = j & 1;
            float ov = sm[8384 + t];
            float fl = floorf(ov);
            int kc = d ? (tap % 3) : (tap / 3);
            ipar[(n * 9 + tap) * 2 + d] = kc - 1 + (int)fl;
            fpar[(n * 9 + tap) * 2 + d] = ov - fl;
        }
    } else if (b < 145) {
        // A2f slot = ((k*4 + w)*4 + mi)*64 + l ; elem = slot*8 + j
        int slot = (b - 1) * 256 + t;
        int l = slot & 63;
        int mi = (slot >> 6) & 3;
        int w = (slot >> 8) & 3;
        int k = slot >> 10;                 // 0..35
        int row = w * 64 + mi * 16 + (l & 15);
        int kq = l >> 4;
        unsigned short v[8];
#pragma unroll
        for (int j = 0; j < 8; ++j) {
            int kcol = k * 32 + kq * 8 + j;  // < 1152
            int tap = kcol >> 7, c = kcol & 127;
            v[j] = f2bf(tw[(row * 128 + c) * 9 + tap]);
        }
        unsigned p0 = (unsigned)v[0] | ((unsigned)v[1] << 16);
        unsigned p1 = (unsigned)v[2] | ((unsigned)v[3] << 16);
        unsigned p2 = (unsigned)v[4] | ((unsigned)v[5] << 16);
        unsigned p3 = (unsigned)v[6] | ((unsigned)v[7] << 16);
        *(uint4*)(A2f + slot * 8) = make_uint4(p0, p1, p2, p3);
    } else if (b < 289) {
        // Awf slot = ((k*2 + wm)*4 + mi)*64 + l
        int slot = (b - 145) * 256 + t;
        int l = slot & 63;
        int mi = (slot >> 6) & 3;
        int wm = (slot >> 8) & 1;
        int k = slot >> 9;                  // 0..71
        int row = wm * 64 + mi * 16 + (l & 15);
        int kq = l >> 4;
        unsigned short v[8];
#pragma unroll
        for (int j = 0; j < 8; ++j) {
            int kcol = k * 32 + kq * 8 + j;  // < 2304
            int t9 = kcol >> 8, ci = kcol & 255;
            int ky = t9 / 3, kx = t9 - ky * 3;
            v[j] = f2bf(tw[(ci * 128 + row) * 9 + (2 - ky) * 3 + (2 - kx)]);
        }
        unsigned p0 = (unsigned)v[0] | ((unsigned)v[1] << 16);
        unsigned p1 = (unsigned)v[2] | ((unsigned)v[3] << 16);
        unsigned p2 = (unsigned)v[4] | ((unsigned)v[5] << 16);
        unsigned p3 = (unsigned)v[6] | ((unsigned)v[7] << 16);
        *(uint4*)(Awf + slot * 8) = make_uint4(p0, p1, p2, p3);
    } else {
        int bb = b - 289;
        int h = bb & 63, cq = (bb >> 6) & 3, n = bb >> 8;
        int c0 = cq * 64;
        {
            int wcol = t & 63, sub = t >> 6;
            for (int r = 0; r < 16; ++r) {
                int ci_l = r * 4 + sub;
                sm[ci_l * 65 + wcol] = x[((n * 256 + c0 + ci_l) * 64 + h) * 64 + wcol];
            }
        }
        __syncthreads();
        int wcol = t >> 2, cg = t & 3;
        unsigned short* dst = xp + (size_t)n * (65 * 65 * 256) + (h * 65 + wcol) * 256 + c0 + cg * 16;
        unsigned pk[8];
#pragma unroll
        for (int j = 0; j < 8; ++j)
            pk[j] = pk2(sm[(cg * 16 + 2 * j) * 65 + wcol], sm[(cg * 16 + 2 * j + 1) * 65 + wcol]);
        *(uint4*)dst = make_uint4(pk[0], pk[1], pk[2], pk[3]);
        *(uint4*)(dst + 8) = make_uint4(pk[4], pk[5], pk[6], pk[7]);
    }
}

// ============ tconv: parity-decomposed MFMA GEMM, A in registers, B double-buffered ============
__global__ __launch_bounds__(256) void k_tconv3(const unsigned short* __restrict__ xp,
                                                const unsigned short* __restrict__ Awf,
                                                unsigned short* __restrict__ upp) {
    __shared__ unsigned short Bs[2][64][40];
    __shared__ int st9[4];
    __shared__ int sbb[4];
    int t = threadIdx.x;
    int b = blockIdx.x;
    int phase = b >> 8, jj = b & 255;
    int n = jj >> 7, xpar = ((jj >> 6) & 1) ^ phase, yh = jj & 63;
    int y = yh * 2 + phase;
    const unsigned short* xpn = xp + (size_t)n * (65 * 65 * 256);

    int lane = t & 63, w = t >> 6;
    int col = lane & 15, q = lane >> 4;
    int wm = w >> 1, wn = w & 1;
    int bx = t >> 2, bcg = t & 3;
    int boff = bx * 256 + bcg * 8;

    int kys[2], kxs[2], nky, nkx;
    if (phase) { kys[0] = 0; kys[1] = 2; nky = 2; } else { kys[0] = 1; kys[1] = 1; nky = 1; }
    if (xpar)  { kxs[0] = 0; kxs[1] = 2; nkx = 2; } else { kxs[0] = 1; kxs[1] = 1; nkx = 1; }
    int nslots = nky * nkx;
    if (t < nslots) {
        int a1 = t / nkx, a2 = t % nkx;
        int ky = kys[a1], kx = kxs[a2];
        st9[t] = ky * 3 + kx;
        int d2 = (y + ky - 1) >> 1;
        int s = (xpar + kx - 1) >> 1;
        sbb[t] = (d2 * 65 + s) * 256;
    }
    int NT = nslots * 8;

    f32x4 acc[4][2];
#pragma unroll
    for (int mi = 0; mi < 4; ++mi)
#pragma unroll
        for (int ni = 0; ni < 2; ++ni) acc[mi][ni] = (f32x4){0.f, 0.f, 0.f, 0.f};

    __syncthreads();   // st9/sbb visible

    const unsigned short* Afw = Awf + wm * 2048 + lane * 8;  // + k*4096 + mi*512
    s16x8 a_cur[4], a_nxt[4];

    // prologue: chunk 0
    {
        int kAw0 = st9[0] * 8;
        uint4 bv = *(const uint4*)(xpn + sbb[0] + boff);
        *(uint4*)&Bs[0][bx][bcg * 8] = bv;
#pragma unroll
        for (int mi = 0; mi < 4; ++mi)
            a_cur[mi] = *(const s16x8*)(Afw + kAw0 * 4096 + mi * 512);
    }
    __syncthreads();

    for (int cc = 0; cc < NT; ++cc) {
        int cc1 = cc + 1;
        uint4 bv;
        if (cc1 < NT) {
            int slot1 = cc1 >> 3, cb1 = cc1 & 7;
            int t9v = st9[slot1];
            int base = sbb[slot1];
            bv = *(const uint4*)(xpn + base + cb1 * 32 + boff);
            int kAw1 = t9v * 8 + cb1;
#pragma unroll
            for (int mi = 0; mi < 4; ++mi)
                a_nxt[mi] = *(const s16x8*)(Afw + kAw1 * 4096 + mi * 512);
        }
        s16x8 bb[2];
#pragma unroll
        for (int ni = 0; ni < 2; ++ni)
            bb[ni] = *(const s16x8*)&Bs[cc & 1][wn * 32 + ni * 16 + col][q * 8];
#pragma unroll
        for (int mi = 0; mi < 4; ++mi)
#pragma unroll
            for (int ni = 0; ni < 2; ++ni)
                acc[mi][ni] = __builtin_amdgcn_mfma_f32_16x16x32_bf16(a_cur[mi], bb[ni], acc[mi][ni], 0, 0, 0);
        if (cc1 < NT) {
            *(uint4*)&Bs[cc1 & 1][bx][bcg * 8] = bv;
#pragma unroll
            for (int mi = 0; mi < 4; ++mi) a_cur[mi] = a_nxt[mi];
        }
        __syncthreads();
    }

    unsigned short* uppn = upp + (size_t)n * (132 * 132 * 128);
#pragma unroll
    for (int mi = 0; mi < 4; ++mi)
#pragma unroll
        for (int ni = 0; ni < 2; ++ni) {
            int co = wm * 64 + mi * 16 + q * 4;
            int p64 = wn * 32 + ni * 16 + col;
            int xg = 2 * p64 + xpar;
            unsigned short* p = uppn + ((y + 2) * 132 + (xg + 2)) * 128 + co;
            unsigned lo = pk2(acc[mi][ni][0], acc[mi][ni][1]);
            unsigned hi = pk2(acc[mi][ni][2], acc[mi][ni][3]);
            *(uint2*)p = make_uint2(lo, hi);
        }
}

// ============ deform: MFMA GEMM, A register fragments, B (bilinear blend) double-buffered ============
__global__ __launch_bounds__(256) void k_deform3(const unsigned short* __restrict__ upp,
                                                 const unsigned short* __restrict__ A2f,
                                                 const int* __restrict__ ipar,
                                                 const float* __restrict__ fpar,
                                                 float* __restrict__ out) {
    __shared__ unsigned short Bs[2][64][40];
    __shared__ int sbase[9];
    __shared__ float4 swt[9];
    int t = threadIdx.x;
    int b = blockIdx.x;
    int xcd = b & 7, j = b >> 3;
    int n = xcd >> 2, band = xcd & 3;
    int y = band * 32 + (j & 31);
    int tx0 = (j >> 5) * 64;
    const unsigned short* uppn = upp + (size_t)n * (132 * 132 * 128);

    int lane = t & 63, w = t >> 6;
    int col = lane & 15, q = lane >> 4;
    int bx = t >> 2, bcg = t & 3;
    int boff = bx * 128 + bcg * 8;

    if (t < 9) {
        int iy = ipar[(n * 9 + t) * 2 + 0], ix = ipar[(n * 9 + t) * 2 + 1];
        float fy = fpar[(n * 9 + t) * 2 + 0], fx = fpar[(n * 9 + t) * 2 + 1];
        sbase[t] = ((y + 2 + iy) * 132 + (tx0 + 2 + ix)) * 128;
        swt[t] = make_float4((1.f - fy) * (1.f - fx), (1.f - fy) * fx, fy * (1.f - fx), fy * fx);
    }

    f32x4 acc[4][4];
#pragma unroll
    for (int mi = 0; mi < 4; ++mi)
#pragma unroll
        for (int ni = 0; ni < 4; ++ni) acc[mi][ni] = (f32x4){0.f, 0.f, 0.f, 0.f};

    __syncthreads();   // sbase/swt visible

    const unsigned short* Afw = A2f + w * 2048 + lane * 8;   // + k*8192 + mi*512
    s16x8 a_cur[4], a_nxt[4];

    // prologue: chunk 0 (tap 0, cb 0)
    {
        const unsigned short* p = uppn + sbase[0] + boff;
        uint4 uA = *(const uint4*)p;
        uint4 uB = *(const uint4*)(p + 128);
        uint4 uC = *(const uint4*)(p + 16896);
        uint4 uD = *(const uint4*)(p + 17024);
        blend_store(uA, uB, uC, uD, swt[0], &Bs[0][bx][bcg * 8]);
#pragma unroll
        for (int mi = 0; mi < 4; ++mi)
            a_cur[mi] = *(const s16x8*)(Afw + mi * 512);
    }
    __syncthreads();

#pragma unroll 2
    for (int k = 0; k < 36; ++k) {
        int k1 = k + 1;
        uint4 uA, uB, uC, uD;
        float4 cw;
        if (k1 < 36) {
            int t1 = k1 >> 2, cb1 = (k1 & 3) * 32;
            int base = sbase[t1];
            cw = swt[t1];
            const unsigned short* p = uppn + base + cb1 + boff;
            uA = *(const uint4*)p;
            uB = *(const uint4*)(p + 128);
            uC = *(const uint4*)(p + 16896);
            uD = *(const uint4*)(p + 17024);
#pragma unroll
            for (int mi = 0; mi < 4; ++mi)
                a_nxt[mi] = *(const s16x8*)(Afw + k1 * 8192 + mi * 512);
        }
        s16x8 bb[4];
#pragma unroll
        for (int ni = 0; ni < 4; ++ni)
            bb[ni] = *(const s16x8*)&Bs[k & 1][ni * 16 + col][q * 8];
#pragma unroll
        for (int mi = 0; mi < 4; ++mi)
#pragma unroll
            for (int ni = 0; ni < 4; ++ni)
                acc[mi][ni] = __builtin_amdgcn_mfma_f32_16x16x32_bf16(a_cur[mi], bb[ni], acc[mi][ni], 0, 0, 0);
        if (k1 < 36) {
            blend_store(uA, uB, uC, uD, cw, &Bs[k1 & 1][bx][bcg * 8]);
#pragma unroll
            for (int mi = 0; mi < 4; ++mi) a_cur[mi] = a_nxt[mi];
        }
        __syncthreads();
    }

#pragma unroll
    for (int mi = 0; mi < 4; ++mi)
#pragma unroll
        for (int ni = 0; ni < 4; ++ni) {
            int o = w * 64 + mi * 16 + q * 4;
            int xg = tx0 + ni * 16 + col;
            float* p = out + (((size_t)(n * 256 + o)) * 128 + y) * 128 + xg;
            p[0]         = acc[mi][ni][0];
            p[16384]     = acc[mi][ni][1];
            p[2 * 16384] = acc[mi][ni][2];
            p[3 * 16384] = acc[mi][ni][3];
        }
}

extern "C" void kernel_launch(void* const* d_in, const int* in_sizes, int n_in,
                              void* d_out, int out_size, void* d_ws, size_t ws_size,
                              hipStream_t stream) {
    const float* x   = (const float*)d_in[0];
    const float* lat = (const float*)d_in[1];
    const float* tw  = (const float*)d_in[2];
    const float* w1  = (const float*)d_in[3];
    const float* b1  = (const float*)d_in[4];
    const float* w2  = (const float*)d_in[5];
    const float* b2  = (const float*)d_in[6];
    float* out = (float*)d_out;

    char* ws = (char*)d_ws;
    // upp bf16 halo2: 2*132*132*128*2 = 8,921,088 @ 0
    // xp  bf16 pad+1: 2*65*65*256*2   = 4,326,400 @ 8,921,088   (one memset covers both)
    // A2f: 294912*2 = 589,824 @ 13,247,488
    // Awf: 294912*2 = 589,824 @ 13,837,312
    unsigned short* upp = (unsigned short*)ws;
    unsigned short* xp  = (unsigned short*)(ws + 8921088);
    unsigned short* A2f = (unsigned short*)(ws + 13247488);
    unsigned short* Awf = (unsigned short*)(ws + 13837312);
    int*   ipar         = (int*)(ws + 14427136);
    float* fpar         = (float*)(ws + 14427424);

    hipMemsetAsync(ws, 0, 13247488, stream);
    k_prep<<<801, 256, 0, stream>>>(x, lat, tw, w1, b1, w2, b2, xp, A2f, Awf, ipar, fpar);
    k_tconv3<<<512, 256, 0, stream>>>(xp, Awf, upp);
    k_deform3<<<512, 256, 0, stream>>>(upp, A2f, ipar, fpar, out);
}